// Round 2
// baseline (2860.553 us; speedup 1.0000x reference)
//
#include <hip/hip_runtime.h>
#include <hip/hip_bf16.h>
#include <cstdint>
#include <cstddef>

// Problem constants (fixed instance).
constexpr int N       = 100000;     // neurons
constexpr int NNZ     = 6400000;    // edges
constexpr int B       = 8;          // batch
constexpr int T       = 8;          // timesteps
constexpr int S       = 5000;       // sensory neurons
constexpr int BIN_BITS = 7;
constexpr int BIN     = 1 << BIN_BITS;               // 128 rows per bin
constexpr int NBINS   = (N + BIN - 1) / BIN;         // 782
constexpr int CHUNK   = 16384;                       // edges per sort block
constexpr int NCHUNKS = (NNZ + CHUNK - 1) / CHUNK;   // 391
constexpr int ITERS   = CHUNK / 256;                 // 64
constexpr float THRESH = 0.01f;

// ---------- prep: per-neuron slope / softplus(bias) ----------
__global__ void k_precompute_sb(const int* __restrict__ gi,
                                const float* __restrict__ slope,
                                const float* __restrict__ raw_biases,
                                float* __restrict__ slopeN,
                                float* __restrict__ biasN) {
    int i = blockIdx.x * 256 + threadIdx.x;
    if (i < N) {
        int g = gi[i];
        slopeN[i] = slope[g];
        float rb = raw_biases[g];
        biasN[i] = (rb > 20.0f) ? rb : log1pf(expf(rb));   // softplus
    }
}

// ---------- pass 1: per-(bin,chunk) histogram ----------
__global__ void k_hist(const int* __restrict__ rows, unsigned* __restrict__ counts) {
    __shared__ unsigned hist[NBINS];
    int tid = threadIdx.x, chunk = blockIdx.x;
    for (int i = tid; i < NBINS; i += 256) hist[i] = 0;
    __syncthreads();
    int base = chunk * CHUNK;
    #pragma unroll 4
    for (int it = 0; it < ITERS; ++it) {
        int e = base + it * 256 + tid;
        if (e < NNZ) atomicAdd(&hist[((unsigned)rows[e]) >> BIN_BITS], 1u);
    }
    __syncthreads();
    for (int i = tid; i < NBINS; i += 256) counts[(size_t)i * NCHUNKS + chunk] = hist[i];
}

// ---------- pass 2a: per-bin exclusive scan across chunks ----------
__global__ void k_scan_chunks(unsigned* __restrict__ counts, unsigned* __restrict__ binTot) {
    int bin = blockIdx.x, lane = threadIdx.x;   // 64 threads
    unsigned carry = 0;
    for (int bse = 0; bse < NCHUNKS; bse += 64) {
        int idx = bse + lane;
        unsigned v = (idx < NCHUNKS) ? counts[(size_t)bin * NCHUNKS + idx] : 0u;
        unsigned x = v;
        #pragma unroll
        for (int off = 1; off < 64; off <<= 1) {
            unsigned y = __shfl_up(x, off, 64);
            if (lane >= off) x += y;
        }
        if (idx < NCHUNKS) counts[(size_t)bin * NCHUNKS + idx] = x - v + carry;
        carry += __shfl(x, 63, 64);
    }
    if (lane == 0) binTot[bin] = carry;
}

// ---------- pass 2b: exclusive scan over bins, PADDED to even sizes ----------
__global__ void k_scan_bins(const unsigned* __restrict__ binTot, unsigned* __restrict__ binBase) {
    int lane = threadIdx.x;   // 64 threads, 1 block
    unsigned carry = 0;
    for (int bse = 0; bse < NBINS; bse += 64) {
        int idx = bse + lane;
        unsigned v = (idx < NBINS) ? ((binTot[idx] + 1u) & ~1u) : 0u;  // round up to even
        unsigned x = v;
        #pragma unroll
        for (int off = 1; off < 64; off <<= 1) {
            unsigned y = __shfl_up(x, off, 64);
            if (lane >= off) x += y;
        }
        if (idx < NBINS) binBase[idx] = x - v + carry;
        carry += __shfl(x, 63, 64);
    }
    if (lane == 0) binBase[NBINS] = carry;   // == padded total
}

// ---------- pass 3: scatter into packed binned format ----------
__global__ void k_scatter(const int* __restrict__ rows, const int* __restrict__ cols,
                          const float* __restrict__ vals,
                          const unsigned* __restrict__ binBase,
                          const unsigned* __restrict__ counts,
                          uint2* __restrict__ pk) {
    __shared__ unsigned cursor[NBINS];
    int tid = threadIdx.x, chunk = blockIdx.x;
    for (int i = tid; i < NBINS; i += 256)
        cursor[i] = binBase[i] + counts[(size_t)i * NCHUNKS + chunk];
    __syncthreads();
    int base = chunk * CHUNK;
    for (int it = 0; it < ITERS; ++it) {
        int e = base + it * 256 + tid;
        if (e < NNZ) {
            unsigned r = (unsigned)rows[e];
            unsigned c = (unsigned)cols[e];
            float    v = vals[e];
            unsigned bin = r >> BIN_BITS, lr = r & (BIN - 1);
            unsigned pos = atomicAdd(&cursor[bin], 1u);
            pk[pos] = make_uint2(__float_as_uint(v), c | (lr << 17));
        }
    }
}

// ---------- fill the 1-edge pad slot of odd-sized bins with a zero edge ----------
__global__ void k_padfill(const unsigned* __restrict__ binTot,
                          const unsigned* __restrict__ binBase,
                          uint2* __restrict__ pk) {
    int i = blockIdx.x * 256 + threadIdx.x;
    if (i < NBINS && (binTot[i] & 1u))
        pk[binBase[i] + binTot[i]] = make_uint2(0u, 0u);   // v=0, c=0, lr=0
}

// ---------- sensory injection (clip + scatter-add) ----------
__global__ void k_sensory(const float* __restrict__ inputs, const int* __restrict__ sidx,
                          float* __restrict__ F, int t) {
    int idx = blockIdx.x * 256 + threadIdx.x;
    if (idx < S * B) {
        int s = idx >> 3, b = idx & 7;
        float val = inputs[((size_t)b * S + s) * T + t];
        val = (val >= THRESH) ? fminf(val, 1.0f) : 0.0f;
        atomicAdd(&F[(size_t)sidx[s] * B + b], val);
    }
}

// ---------- main step: binned SpMM + activation ----------
__global__ __launch_bounds__(512, 8)
void k_step(const uint2* __restrict__ pk,
            const unsigned* __restrict__ binBase,
            const float* __restrict__ Fin,
            const float* __restrict__ slopeN,
            const float* __restrict__ biasN,
            float* __restrict__ Fout,
            __hip_bfloat16* __restrict__ st) {   // st = ST + t*N*B, layout [row][b]
    __shared__ float acc[B][BIN];    // 4 KB; fixed-b atomic across lanes -> bank = lr%32
    int tid = threadIdx.x, bin = blockIdx.x;
    for (int i = tid; i < B * BIN; i += 512) ((float*)acc)[i] = 0.0f;
    __syncthreads();

    unsigned start = binBase[bin], end = binBase[bin + 1];   // even-sized range
    const uint4* p4 = (const uint4*)(pk + start);            // 16B-aligned (start even)
    unsigned npair = (end - start) >> 1;
    #pragma unroll 2
    for (unsigned i = tid; i < npair; i += 512) {
        uint4 q = p4[i];
        float v0 = __uint_as_float(q.x);
        float v1 = __uint_as_float(q.z);
        unsigned c0 = q.y & 0x1FFFFu, r0 = q.y >> 17;
        unsigned c1 = q.w & 0x1FFFFu, r1 = q.w >> 17;
        const float4* fx0 = (const float4*)(Fin + (size_t)c0 * B);
        const float4* fx1 = (const float4*)(Fin + (size_t)c1 * B);
        float4 a0 = fx0[0], a1 = fx0[1];
        float4 b0 = fx1[0], b1 = fx1[1];
        atomicAdd(&acc[0][r0], v0 * a0.x);
        atomicAdd(&acc[1][r0], v0 * a0.y);
        atomicAdd(&acc[2][r0], v0 * a0.z);
        atomicAdd(&acc[3][r0], v0 * a0.w);
        atomicAdd(&acc[4][r0], v0 * a1.x);
        atomicAdd(&acc[5][r0], v0 * a1.y);
        atomicAdd(&acc[6][r0], v0 * a1.z);
        atomicAdd(&acc[7][r0], v0 * a1.w);
        atomicAdd(&acc[0][r1], v1 * b0.x);
        atomicAdd(&acc[1][r1], v1 * b0.y);
        atomicAdd(&acc[2][r1], v1 * b0.z);
        atomicAdd(&acc[3][r1], v1 * b0.w);
        atomicAdd(&acc[4][r1], v1 * b1.x);
        atomicAdd(&acc[5][r1], v1 * b1.y);
        atomicAdd(&acc[6][r1], v1 * b1.z);
        atomicAdd(&acc[7][r1], v1 * b1.w);
    }
    __syncthreads();

    if (tid < BIN) {
        int row = bin * BIN + tid;
        if (row < N) {
            float sl = slopeN[row], bi = biasN[row];
            float o[B];
            #pragma unroll
            for (int b = 0; b < B; ++b) {
                float y = sl * acc[b][tid] + bi;
                y = (y >= THRESH) ? y : 0.0f;
                o[b] = tanhf(y);
            }
            // f32 state for recurrence (coalesced 32B/row)
            float4* fo = (float4*)(Fout + (size_t)row * B);
            fo[0] = make_float4(o[0], o[1], o[2], o[3]);
            fo[1] = make_float4(o[4], o[5], o[6], o[7]);
            // bf16 staging for output transpose (coalesced 16B/row)
            union { __hip_bfloat16 h[8]; uint4 u; } pack;
            #pragma unroll
            for (int b = 0; b < B; ++b) pack.h[b] = __float2bfloat16(o[b]);
            *((uint4*)(st + (size_t)row * B)) = pack.u;
        }
    }
}

// ---------- final transpose: ST (T,N,B) bf16 -> out (B,N,T) f32 ----------
__global__ void k_transpose(const __hip_bfloat16* __restrict__ ST, float* __restrict__ out) {
    int g = blockIdx.x * 256 + threadIdx.x;      // g = b*N + row
    if (g >= N * B) return;
    int b = g / N;
    int row = g - b * N;
    float o[T];
    #pragma unroll
    for (int t = 0; t < T; ++t)
        o[t] = __bfloat162float(ST[(size_t)t * N * B + (size_t)row * B + b]);
    float4* dst = (float4*)(out + (size_t)g * T);   // coalesced 32B per thread
    dst[0] = make_float4(o[0], o[1], o[2], o[3]);
    dst[1] = make_float4(o[4], o[5], o[6], o[7]);
}

static inline size_t align_up(size_t x, size_t a) { return (x + a - 1) & ~(a - 1); }

extern "C" void kernel_launch(void* const* d_in, const int* in_sizes, int n_in,
                              void* d_out, int out_size, void* d_ws, size_t ws_size,
                              hipStream_t stream) {
    const float* vals  = (const float*)d_in[0];
    const int*   rows  = (const int*)d_in[1];
    const int*   cols  = (const int*)d_in[2];
    const int*   sidx  = (const int*)d_in[3];
    const int*   gi    = (const int*)d_in[4];
    const float* slope = (const float*)d_in[5];
    const float* rawb  = (const float*)d_in[6];
    const float* inputs = (const float*)d_in[7];
    float* out = (float*)d_out;

    // workspace layout (~73 MB)
    char* ws = (char*)d_ws;
    size_t off = 0;
    uint2*    pk      = (uint2*)(ws + off);    off = align_up(off + (size_t)(NNZ + NBINS) * 8, 256);
    unsigned* counts  = (unsigned*)(ws + off); off = align_up(off + (size_t)NBINS * NCHUNKS * 4, 256);
    unsigned* binTot  = (unsigned*)(ws + off); off = align_up(off + (size_t)NBINS * 4, 256);
    unsigned* binBase = (unsigned*)(ws + off); off = align_up(off + (size_t)(NBINS + 1) * 4, 256);
    float*    F0      = (float*)(ws + off);    off = align_up(off + (size_t)N * B * 4, 256);
    float*    F1      = (float*)(ws + off);    off = align_up(off + (size_t)N * B * 4, 256);
    __hip_bfloat16* ST = (__hip_bfloat16*)(ws + off); off = align_up(off + (size_t)T * N * B * 2, 256);
    float*    slopeN  = (float*)(ws + off);    off = align_up(off + (size_t)N * 4, 256);
    float*    biasN   = (float*)(ws + off);    off = align_up(off + (size_t)N * 4, 256);
    if (off > ws_size) return;   // workspace too small — will show as validation failure

    // prep
    k_precompute_sb<<<(N + 255) / 256, 256, 0, stream>>>(gi, slope, rawb, slopeN, biasN);
    // counting sort: hist -> scan chunks -> scan bins (padded) -> scatter -> padfill
    k_hist<<<NCHUNKS, 256, 0, stream>>>(rows, counts);
    k_scan_chunks<<<NBINS, 64, 0, stream>>>(counts, binTot);
    k_scan_bins<<<1, 64, 0, stream>>>(binTot, binBase);
    k_scatter<<<NCHUNKS, 256, 0, stream>>>(rows, cols, vals, binBase, counts, pk);
    k_padfill<<<(NBINS + 255) / 256, 256, 0, stream>>>(binTot, binBase, pk);

    // t=0 state: zeros + sensory input
    hipMemsetAsync(F0, 0, (size_t)N * B * 4, stream);
    k_sensory<<<(S * B + 255) / 256, 256, 0, stream>>>(inputs, sidx, F0, 0);

    float* Fcur = F0;
    float* Fnxt = F1;
    for (int t = 0; t < T; ++t) {
        k_step<<<NBINS, 512, 0, stream>>>(pk, binBase, Fcur, slopeN, biasN, Fnxt,
                                          ST + (size_t)t * N * B);
        if (t + 1 < T)
            k_sensory<<<(S * B + 255) / 256, 256, 0, stream>>>(inputs, sidx, Fnxt, t + 1);
        float* tmp = Fcur; Fcur = Fnxt; Fnxt = tmp;
    }
    k_transpose<<<(N * B + 255) / 256, 256, 0, stream>>>(ST, out);
}

// Round 4
// 592.094 us; speedup vs baseline: 4.8312x; 4.8312x over previous
//
#include <hip/hip_runtime.h>
#include <cstdint>
#include <cstddef>

// Problem constants (fixed instance).
constexpr int N       = 100000;     // neurons
constexpr int NNZ     = 6400000;    // edges
constexpr int B       = 8;          // batch
constexpr int T       = 8;          // timesteps
constexpr int S       = 5000;       // sensory neurons
constexpr int BIN_BITS = 7;
constexpr int BIN     = 1 << BIN_BITS;               // 128 rows per bin
constexpr int NBINS   = (N + BIN - 1) / BIN;         // 782
constexpr int CHUNK   = 16384;                       // edges per sort block
constexpr int NCHUNKS = (NNZ + CHUNK - 1) / CHUNK;   // 391
constexpr int ITERS   = CHUNK / 256;                 // 64
constexpr float THRESH = 0.01f;

// ---------- prep: per-neuron slope / softplus(bias) ----------
__global__ void k_precompute_sb(const int* __restrict__ gi,
                                const float* __restrict__ slope,
                                const float* __restrict__ raw_biases,
                                float* __restrict__ slopeN,
                                float* __restrict__ biasN) {
    int i = blockIdx.x * 256 + threadIdx.x;
    if (i < N) {
        int g = gi[i];
        slopeN[i] = slope[g];
        float rb = raw_biases[g];
        biasN[i] = (rb > 20.0f) ? rb : log1pf(expf(rb));   // softplus
    }
}

// ---------- pass 1: per-(bin,chunk) histogram ----------
__global__ void k_hist(const int* __restrict__ rows, unsigned* __restrict__ counts) {
    __shared__ unsigned hist[NBINS];
    int tid = threadIdx.x, chunk = blockIdx.x;
    for (int i = tid; i < NBINS; i += 256) hist[i] = 0;
    __syncthreads();
    int base = chunk * CHUNK;
    #pragma unroll 4
    for (int it = 0; it < ITERS; ++it) {
        int e = base + it * 256 + tid;
        if (e < NNZ) atomicAdd(&hist[((unsigned)rows[e]) >> BIN_BITS], 1u);
    }
    __syncthreads();
    for (int i = tid; i < NBINS; i += 256) counts[(size_t)i * NCHUNKS + chunk] = hist[i];
}

// ---------- pass 2a: per-bin exclusive scan across chunks ----------
__global__ void k_scan_chunks(unsigned* __restrict__ counts, unsigned* __restrict__ binTot) {
    int bin = blockIdx.x, lane = threadIdx.x;   // 64 threads
    unsigned carry = 0;
    for (int bse = 0; bse < NCHUNKS; bse += 64) {
        int idx = bse + lane;
        unsigned v = (idx < NCHUNKS) ? counts[(size_t)bin * NCHUNKS + idx] : 0u;
        unsigned x = v;
        #pragma unroll
        for (int off = 1; off < 64; off <<= 1) {
            unsigned y = __shfl_up(x, off, 64);
            if (lane >= off) x += y;
        }
        if (idx < NCHUNKS) counts[(size_t)bin * NCHUNKS + idx] = x - v + carry;
        carry += __shfl(x, 63, 64);
    }
    if (lane == 0) binTot[bin] = carry;
}

// ---------- pass 2b: exclusive scan over bins ----------
__global__ void k_scan_bins(const unsigned* __restrict__ binTot, unsigned* __restrict__ binBase) {
    int lane = threadIdx.x;   // 64 threads, 1 block
    unsigned carry = 0;
    for (int bse = 0; bse < NBINS; bse += 64) {
        int idx = bse + lane;
        unsigned v = (idx < NBINS) ? binTot[idx] : 0u;
        unsigned x = v;
        #pragma unroll
        for (int off = 1; off < 64; off <<= 1) {
            unsigned y = __shfl_up(x, off, 64);
            if (lane >= off) x += y;
        }
        if (idx < NBINS) binBase[idx] = x - v + carry;
        carry += __shfl(x, 63, 64);
    }
    if (lane == 0) binBase[NBINS] = carry;   // == NNZ
}

// ---------- pass 3: scatter into binned format (val, col|lr<<17) ----------
__global__ void k_scatter(const int* __restrict__ rows, const int* __restrict__ cols,
                          const float* __restrict__ vals,
                          const unsigned* __restrict__ binBase,
                          const unsigned* __restrict__ counts,
                          uint2* __restrict__ pk) {
    __shared__ unsigned cursor[NBINS];
    int tid = threadIdx.x, chunk = blockIdx.x;
    for (int i = tid; i < NBINS; i += 256)
        cursor[i] = binBase[i] + counts[(size_t)i * NCHUNKS + chunk];
    __syncthreads();
    int base = chunk * CHUNK;
    for (int it = 0; it < ITERS; ++it) {
        int e = base + it * 256 + tid;
        if (e < NNZ) {
            unsigned r = (unsigned)rows[e];
            unsigned c = (unsigned)cols[e];
            float    v = vals[e];
            unsigned bin = r >> BIN_BITS, lr = r & (BIN - 1);
            unsigned pos = atomicAdd(&cursor[bin], 1u);
            pk[pos] = make_uint2(__float_as_uint(v), c | (lr << 17));
        }
    }
}

// ---------- pass 4: within-bin counting sort by local row -> CSR ----------
__global__ void k_sortbin(const uint2* __restrict__ pk,
                          const unsigned* __restrict__ binBase,
                          uint2* __restrict__ pk2,
                          unsigned* __restrict__ rowPtr) {
    __shared__ unsigned cnt[BIN];
    __shared__ unsigned ofs[BIN];
    int tid = threadIdx.x, bin = blockIdx.x;
    if (tid < BIN) cnt[tid] = 0;
    __syncthreads();
    unsigned s = binBase[bin], e = binBase[bin + 1];
    for (unsigned i = s + tid; i < e; i += 256)
        atomicAdd(&cnt[pk[i].y >> 17], 1u);   // int LDS atomic (native, fast)
    __syncthreads();
    if (tid < BIN) ofs[tid] = cnt[tid];
    __syncthreads();
    // Hillis-Steele inclusive scan of 128 entries
    for (int off = 1; off < BIN; off <<= 1) {
        unsigned v = (tid < BIN && tid >= off) ? ofs[tid - off] : 0u;
        __syncthreads();
        if (tid < BIN) ofs[tid] += v;
        __syncthreads();
    }
    if (tid < BIN) {
        unsigned excl = ofs[tid] - cnt[tid];
        cnt[tid] = s + excl;                 // running cursor per local row
        int row = bin * BIN + tid;
        if (row < N) rowPtr[row] = s + excl;
    }
    if (bin == NBINS - 1 && tid == 0) rowPtr[N] = e;
    __syncthreads();
    for (unsigned i = s + tid; i < e; i += 256) {
        uint2 p = pk[i];
        unsigned pos = atomicAdd(&cnt[p.y >> 17], 1u);
        pk2[pos] = make_uint2(p.x, p.y & 0x1FFFFu);   // (val, col)
    }
}

// ---------- sensory injection (clip + scatter-add) ----------
__global__ void k_sensory(const float* __restrict__ inputs, const int* __restrict__ sidx,
                          float* __restrict__ X, int t) {
    int idx = blockIdx.x * 256 + threadIdx.x;
    if (idx < S * B) {
        int s = idx >> 3, b = idx & 7;
        float val = inputs[((size_t)b * S + s) * T + t];
        val = (val >= THRESH) ? fminf(val, 1.0f) : 0.0f;
        atomicAdd(&X[(size_t)sidx[s] * B + b], val);
    }
}

// ---------- main step: CSR SpMV, one wave per row, register accumulation ----------
__global__ __launch_bounds__(256)
void k_step(const uint2* __restrict__ pk2,
            const unsigned* __restrict__ rowPtr,
            const float* __restrict__ Xin,
            const float* __restrict__ slopeN,
            const float* __restrict__ biasN,
            float* __restrict__ Sout,     // activation output (N,B) = this step's state
            float* __restrict__ Xnext) {  // copy for next step's input (gets sensory added)
    int wid  = (int)((blockIdx.x * 256u + threadIdx.x) >> 6);   // row = global wave id
    int lane = threadIdx.x & 63;
    if (wid >= N) return;
    unsigned e0 = rowPtr[wid], e1 = rowPtr[wid + 1];
    float a0=0.f,a1=0.f,a2=0.f,a3=0.f,a4=0.f,a5=0.f,a6=0.f,a7=0.f;
    for (unsigned e = e0 + lane; e < e1; e += 64) {
        uint2 p = pk2[e];
        float v = __uint_as_float(p.x);
        const float4* fx = (const float4*)(Xin + (size_t)p.y * B);
        float4 x0 = fx[0], x1 = fx[1];
        a0 += v * x0.x; a1 += v * x0.y; a2 += v * x0.z; a3 += v * x0.w;
        a4 += v * x1.x; a5 += v * x1.y; a6 += v * x1.z; a7 += v * x1.w;
    }
    // Fold 8 accumulators so lane ends up holding total for b = lane&7.
    int l1 = lane & 1, l2 = lane & 2, l4 = lane & 4;
    float k0 = l1 ? a1 : a0, s0 = l1 ? a0 : a1;
    float k1 = l1 ? a3 : a2, s1 = l1 ? a2 : a3;
    float k2 = l1 ? a5 : a4, s2 = l1 ? a4 : a5;
    float k3 = l1 ? a7 : a6, s3 = l1 ? a6 : a7;
    k0 += __shfl_xor(s0, 1, 64);
    k1 += __shfl_xor(s1, 1, 64);
    k2 += __shfl_xor(s2, 1, 64);
    k3 += __shfl_xor(s3, 1, 64);
    float m0 = l2 ? k1 : k0, t0 = l2 ? k0 : k1;
    float m1 = l2 ? k3 : k2, t1 = l2 ? k2 : k3;
    m0 += __shfl_xor(t0, 2, 64);
    m1 += __shfl_xor(t1, 2, 64);
    float r = l4 ? m1 : m0, u = l4 ? m0 : m1;
    r += __shfl_xor(u, 4, 64);
    r += __shfl_xor(r, 8, 64);
    r += __shfl_xor(r, 16, 64);
    r += __shfl_xor(r, 32, 64);
    // activation
    float sl = slopeN[wid], bi = biasN[wid];
    float y = sl * r + bi;
    y = (y >= THRESH) ? y : 0.f;
    float o = tanhf(y);
    if (lane < 8) {
        size_t idx = (size_t)wid * B + lane;
        Sout[idx]  = o;
        Xnext[idx] = o;
    }
}

// ---------- final transpose: St (T,N,B) f32 -> out (B,N,T) f32 ----------
__global__ void k_transpose(const float* __restrict__ St, float* __restrict__ out) {
    int g = blockIdx.x * 256 + threadIdx.x;      // g = b*N + r
    if (g >= N * B) return;
    int b = g / N;
    int r = g - b * N;
    float o[T];
    #pragma unroll
    for (int t = 0; t < T; ++t)
        o[t] = St[(size_t)t * N * B + (size_t)r * B + b];
    float4* dst = (float4*)(out + (size_t)g * T);   // coalesced 32B per thread
    dst[0] = make_float4(o[0], o[1], o[2], o[3]);
    dst[1] = make_float4(o[4], o[5], o[6], o[7]);
}

extern "C" void kernel_launch(void* const* d_in, const int* in_sizes, int n_in,
                              void* d_out, int out_size, void* d_ws, size_t ws_size,
                              hipStream_t stream) {
    const float* vals  = (const float*)d_in[0];
    const int*   rows  = (const int*)d_in[1];
    const int*   cols  = (const int*)d_in[2];
    const int*   sidx  = (const int*)d_in[3];
    const int*   gi    = (const int*)d_in[4];
    const float* slope = (const float*)d_in[5];
    const float* rawb  = (const float*)d_in[6];
    const float* inputs = (const float*)d_in[7];
    float* out = (float*)d_out;

    // Workspace layout with time-aliasing (~103 MB):
    // Region A (51.2MB): pk during sort; after k_sortbin reused for St/Xin/slope/bias.
    // Region B (51.2MB): counts during sort prep (1.3MB); then pk2 (written by k_sortbin).
    // Region C: binTot, binBase, rowPtr (persistent, small).
    char* ws = (char*)d_ws;
    uint2*    pk     = (uint2*)ws;                         // [0, 51.2MB)
    float*    St     = (float*)ws;                         // 25.6MB (aliases pk, used after sort)
    float*    Xin0   = (float*)(ws + 25600000);            // 3.2MB
    float*    Xin1   = (float*)(ws + 28800000);            // 3.2MB
    float*    slopeN = (float*)(ws + 32000000);            // 0.4MB
    float*    biasN  = (float*)(ws + 32400000);            // 0.4MB
    char*     wsB    = ws + 51200000;
    uint2*    pk2    = (uint2*)wsB;                        // 51.2MB
    unsigned* counts = (unsigned*)wsB;                     // 1.23MB (dead before pk2 written)
    char*     wsC    = wsB + 51200000;
    unsigned* binTot  = (unsigned*)(wsC);                  // 3.1KB
    unsigned* binBase = (unsigned*)(wsC + 4096);           // 3.1KB
    unsigned* rowPtr  = (unsigned*)(wsC + 8192);           // 400KB
    size_t need = 102400000 + 8192 + (size_t)(N + 1) * 4 + 256;
    if (need > ws_size) return;   // workspace too small

    // ---- one-time sort to CSR ----
    k_hist<<<NCHUNKS, 256, 0, stream>>>(rows, counts);
    k_scan_chunks<<<NBINS, 64, 0, stream>>>(counts, binTot);
    k_scan_bins<<<1, 64, 0, stream>>>(binTot, binBase);
    k_scatter<<<NCHUNKS, 256, 0, stream>>>(rows, cols, vals, binBase, counts, pk);
    k_sortbin<<<NBINS, 256, 0, stream>>>(pk, binBase, pk2, rowPtr);
    // region A now reusable:
    k_precompute_sb<<<(N + 255) / 256, 256, 0, stream>>>(gi, slope, rawb, slopeN, biasN);

    // t=0 input: zeros + sensory
    hipMemsetAsync(Xin0, 0, (size_t)N * B * 4, stream);
    k_sensory<<<(S * B + 255) / 256, 256, 0, stream>>>(inputs, sidx, Xin0, 0);

    float* Xcur = Xin0;
    float* Xnxt = Xin1;
    for (int t = 0; t < T; ++t) {
        // one wave per row: N waves = N/4 blocks of 256 threads  (R3 bug: was 1564 blocks)
        k_step<<<(N + 3) / 4, 256, 0, stream>>>(
            pk2, rowPtr, Xcur, slopeN, biasN, St + (size_t)t * N * B, Xnxt);
        if (t + 1 < T)
            k_sensory<<<(S * B + 255) / 256, 256, 0, stream>>>(inputs, sidx, Xnxt, t + 1);
        float* tmp = Xcur; Xcur = Xnxt; Xnxt = tmp;
    }
    k_transpose<<<(N * B + 255) / 256, 256, 0, stream>>>(St, out);
}

// Round 5
// 562.600 us; speedup vs baseline: 5.0845x; 1.0524x over previous
//
#include <hip/hip_runtime.h>
#include <cstdint>
#include <cstddef>

// Problem constants (fixed instance).
constexpr int N       = 100000;     // neurons
constexpr int NNZ     = 6400000;    // edges
constexpr int B       = 8;          // batch
constexpr int T       = 8;          // timesteps
constexpr int S       = 5000;       // sensory neurons (sensory_indices = arange(S))
constexpr int BIN1_BITS = 8;
constexpr int BIN1    = 1 << BIN1_BITS;              // 256 rows per L1 bin
constexpr int NBINS1  = (N + BIN1 - 1) / BIN1;       // 391
constexpr int CHUNK   = 8192;                        // edges per sort block
constexpr int NCHUNKS = (NNZ + CHUNK - 1) / CHUNK;   // 782
constexpr float THRESH = 0.01f;

// ---------- prep: per-neuron slope / softplus(bias) ----------
__global__ void k_precompute_sb(const int* __restrict__ gi,
                                const float* __restrict__ slope,
                                const float* __restrict__ raw_biases,
                                float* __restrict__ slopeN,
                                float* __restrict__ biasN) {
    int i = blockIdx.x * 256 + threadIdx.x;
    if (i < N) {
        int g = gi[i];
        slopeN[i] = slope[g];
        float rb = raw_biases[g];
        biasN[i] = (rb > 20.0f) ? rb : log1pf(expf(rb));   // softplus
    }
}

// ---------- pass 1: per-(bin,chunk) histogram ----------
__global__ void k_hist(const int* __restrict__ rows, unsigned* __restrict__ counts) {
    __shared__ unsigned hist[NBINS1];
    int tid = threadIdx.x, chunk = blockIdx.x;
    for (int i = tid; i < NBINS1; i += 256) hist[i] = 0;
    __syncthreads();
    int base = chunk * CHUNK;
    #pragma unroll 4
    for (int it = 0; it < CHUNK / 256; ++it) {
        int e = base + it * 256 + tid;
        if (e < NNZ) atomicAdd(&hist[((unsigned)rows[e]) >> BIN1_BITS], 1u);
    }
    __syncthreads();
    for (int i = tid; i < NBINS1; i += 256) counts[(size_t)i * NCHUNKS + chunk] = hist[i];
}

// ---------- pass 2a: per-bin exclusive scan across chunks ----------
__global__ void k_scan_chunks(unsigned* __restrict__ counts, unsigned* __restrict__ binTot) {
    int bin = blockIdx.x, lane = threadIdx.x;   // 64 threads
    unsigned carry = 0;
    for (int bse = 0; bse < NCHUNKS; bse += 64) {
        int idx = bse + lane;
        unsigned v = (idx < NCHUNKS) ? counts[(size_t)bin * NCHUNKS + idx] : 0u;
        unsigned x = v;
        #pragma unroll
        for (int off = 1; off < 64; off <<= 1) {
            unsigned y = __shfl_up(x, off, 64);
            if (lane >= off) x += y;
        }
        if (idx < NCHUNKS) counts[(size_t)bin * NCHUNKS + idx] = x - v + carry;
        carry += __shfl(x, 63, 64);
    }
    if (lane == 0) binTot[bin] = carry;
}

// ---------- pass 2b: exclusive scan over bins ----------
__global__ void k_scan_bins(const unsigned* __restrict__ binTot, unsigned* __restrict__ binBase) {
    int lane = threadIdx.x;   // 64 threads, 1 block
    unsigned carry = 0;
    for (int bse = 0; bse < NBINS1; bse += 64) {
        int idx = bse + lane;
        unsigned v = (idx < NBINS1) ? binTot[idx] : 0u;
        unsigned x = v;
        #pragma unroll
        for (int off = 1; off < 64; off <<= 1) {
            unsigned y = __shfl_up(x, off, 64);
            if (lane >= off) x += y;
        }
        if (idx < NBINS1) binBase[idx] = x - v + carry;
        carry += __shfl(x, 63, 64);
    }
    if (lane == 0) binBase[NBINS1] = carry;   // == NNZ
}

// ---------- pass 3: LDS-staged scatter — sorted-run (coalesced) global writes ----------
__global__ __launch_bounds__(512)
void k_scatter(const int* __restrict__ rows, const int* __restrict__ cols,
               const float* __restrict__ vals,
               const unsigned* __restrict__ binBase,
               const unsigned* __restrict__ counts,
               uint2* __restrict__ pk) {
    __shared__ uint2    stage[CHUNK];      // 64 KB
    __shared__ unsigned lcnt[NBINS1];      // hist, then run-end cursor
    __shared__ unsigned lofs[NBINS1 + 1];  // exclusive scan (run starts)
    __shared__ unsigned gdst[NBINS1];      // global dest base of this chunk's run
    int tid = threadIdx.x, chunk = blockIdx.x;
    int base = chunk * CHUNK;
    for (int i = tid; i < NBINS1; i += 512) lcnt[i] = 0;
    __syncthreads();
    // local histogram
    for (int i = tid; i < CHUNK; i += 512) {
        int e = base + i;
        if (e < NNZ) atomicAdd(&lcnt[((unsigned)rows[e]) >> BIN1_BITS], 1u);
    }
    __syncthreads();
    // exclusive scan of lcnt -> lofs (wave 0, sequential-carry over 64-wide tiles)
    if (tid < 64) {
        unsigned carry = 0;
        for (int bse = 0; bse < NBINS1; bse += 64) {
            int idx = bse + tid;
            unsigned v = (idx < NBINS1) ? lcnt[idx] : 0u;
            unsigned x = v;
            #pragma unroll
            for (int off = 1; off < 64; off <<= 1) {
                unsigned y = __shfl_up(x, off, 64);
                if (tid >= off) x += y;
            }
            if (idx < NBINS1) lofs[idx] = x - v + carry;
            carry += __shfl(x, 63, 64);
        }
        if (tid == 0) lofs[NBINS1] = carry;
    }
    __syncthreads();
    if (tid < NBINS1) {
        lcnt[tid] = lofs[tid];                                      // cursor
        gdst[tid] = binBase[tid] + counts[(size_t)tid * NCHUNKS + chunk];
    }
    __syncthreads();
    // scatter into LDS (sorted by bin)
    for (int i = tid; i < CHUNK; i += 512) {
        int e = base + i;
        if (e < NNZ) {
            unsigned r = (unsigned)rows[e];
            unsigned c = (unsigned)cols[e];
            float    v = vals[e];
            unsigned b1 = r >> BIN1_BITS, lr = r & (BIN1 - 1);
            unsigned pos = atomicAdd(&lcnt[b1], 1u);
            stage[pos] = make_uint2(__float_as_uint(v), c | (lr << 17));
        }
    }
    __syncthreads();
    // write out per-bin runs, lanes -> consecutive addresses (merged bursts)
    int wave = tid >> 6, lane = tid & 63;
    for (int b1 = wave; b1 < NBINS1; b1 += 8) {
        unsigned s = lofs[b1], epos = lcnt[b1];   // run [s, epos)
        unsigned g = gdst[b1];
        for (unsigned j = s + lane; j < epos; j += 64)
            pk[(size_t)g + (j - s)] = stage[j];
    }
}

// ---------- pass 4: within-bin counting sort by local row -> CSR ----------
__global__ __launch_bounds__(256)
void k_sortbin(const uint2* __restrict__ pk,
               const unsigned* __restrict__ binBase,
               uint2* __restrict__ pk2,
               unsigned* __restrict__ rowPtr) {
    __shared__ unsigned cnt[BIN1];
    __shared__ unsigned ofs[BIN1];
    int tid = threadIdx.x, bin = blockIdx.x;
    cnt[tid] = 0;
    __syncthreads();
    unsigned s = binBase[bin], e = binBase[bin + 1];
    for (unsigned i = s + tid; i < e; i += 256)
        atomicAdd(&cnt[pk[i].y >> 17], 1u);   // int LDS atomic
    __syncthreads();
    ofs[tid] = cnt[tid];
    __syncthreads();
    // Hillis-Steele inclusive scan of 256 entries
    for (int off = 1; off < BIN1; off <<= 1) {
        unsigned v = (tid >= off) ? ofs[tid - off] : 0u;
        __syncthreads();
        ofs[tid] += v;
        __syncthreads();
    }
    unsigned excl = ofs[tid] - cnt[tid];
    cnt[tid] = s + excl;                 // running cursor per local row
    int row = bin * BIN1 + tid;
    if (row <= N) rowPtr[row] = s + excl;   // row==N lands here too (last bin)
    __syncthreads();
    for (unsigned i = s + tid; i < e; i += 256) {
        uint2 p = pk[i];
        unsigned pos = atomicAdd(&cnt[p.y >> 17], 1u);
        pk2[pos] = make_uint2(p.x, p.y & 0x1FFFFu);   // (val, col)
    }
}

// ---------- sensory injection for t=0 (clip + scatter-add) ----------
__global__ void k_sensory(const float* __restrict__ inputs, const int* __restrict__ sidx,
                          float* __restrict__ X, int t) {
    int idx = blockIdx.x * 256 + threadIdx.x;
    if (idx < S * B) {
        int s = idx >> 3, b = idx & 7;
        float val = inputs[((size_t)b * S + s) * T + t];
        val = (val >= THRESH) ? fminf(val, 1.0f) : 0.0f;
        atomicAdd(&X[(size_t)sidx[s] * B + b], val);
    }
}

// ---------- main step: CSR SpMV, one wave per row, register accumulation ----------
__global__ __launch_bounds__(256)
void k_step(const uint2* __restrict__ pk2,
            const unsigned* __restrict__ rowPtr,
            const float* __restrict__ Xin,
            const float* __restrict__ slopeN,
            const float* __restrict__ biasN,
            float* __restrict__ Sout,     // activation output (N,B) = this step's state
            float* __restrict__ Xnext,    // next step's input (sensory fused if has_next)
            const float* __restrict__ inputs, int tnext, int has_next) {
    int wid  = (int)((blockIdx.x * 256u + threadIdx.x) >> 6);   // row = global wave id
    int lane = threadIdx.x & 63;
    if (wid >= N) return;
    unsigned e0 = rowPtr[wid], e1 = rowPtr[wid + 1];
    float a0=0.f,a1=0.f,a2=0.f,a3=0.f,a4=0.f,a5=0.f,a6=0.f,a7=0.f;
    for (unsigned e = e0 + lane; e < e1; e += 64) {
        uint2 p = pk2[e];
        float v = __uint_as_float(p.x);
        const float4* fx = (const float4*)(Xin + (size_t)p.y * B);
        float4 x0 = fx[0], x1 = fx[1];
        a0 += v * x0.x; a1 += v * x0.y; a2 += v * x0.z; a3 += v * x0.w;
        a4 += v * x1.x; a5 += v * x1.y; a6 += v * x1.z; a7 += v * x1.w;
    }
    // Fold 8 accumulators so lane ends up holding total for b = lane&7.
    int l1 = lane & 1, l2 = lane & 2, l4 = lane & 4;
    float k0 = l1 ? a1 : a0, s0 = l1 ? a0 : a1;
    float k1 = l1 ? a3 : a2, s1 = l1 ? a2 : a3;
    float k2 = l1 ? a5 : a4, s2 = l1 ? a4 : a5;
    float k3 = l1 ? a7 : a6, s3 = l1 ? a6 : a7;
    k0 += __shfl_xor(s0, 1, 64);
    k1 += __shfl_xor(s1, 1, 64);
    k2 += __shfl_xor(s2, 1, 64);
    k3 += __shfl_xor(s3, 1, 64);
    float m0 = l2 ? k1 : k0, t0 = l2 ? k0 : k1;
    float m1 = l2 ? k3 : k2, t1 = l2 ? k2 : k3;
    m0 += __shfl_xor(t0, 2, 64);
    m1 += __shfl_xor(t1, 2, 64);
    float r = l4 ? m1 : m0, u = l4 ? m0 : m1;
    r += __shfl_xor(u, 4, 64);
    r += __shfl_xor(r, 8, 64);
    r += __shfl_xor(r, 16, 64);
    r += __shfl_xor(r, 32, 64);
    // activation
    float sl = slopeN[wid], bi = biasN[wid];
    float y = sl * r + bi;
    y = (y >= THRESH) ? y : 0.f;
    float o = tanhf(y);
    if (lane < 8) {
        size_t idx = (size_t)wid * B + lane;
        Sout[idx] = o;
        float xn = o;
        if (has_next && wid < S) {   // sensory_indices == arange(S)
            float val = inputs[((size_t)lane * S + wid) * T + tnext];
            val = (val >= THRESH) ? fminf(val, 1.0f) : 0.0f;
            xn += val;
        }
        Xnext[idx] = xn;
    }
}

// ---------- final transpose: St (T,N,B) f32 -> out (B,N,T) f32 ----------
__global__ void k_transpose(const float* __restrict__ St, float* __restrict__ out) {
    int g = blockIdx.x * 256 + threadIdx.x;      // g = b*N + r
    if (g >= N * B) return;
    int b = g / N;
    int r = g - b * N;
    float o[T];
    #pragma unroll
    for (int t = 0; t < T; ++t)
        o[t] = St[(size_t)t * N * B + (size_t)r * B + b];
    float4* dst = (float4*)(out + (size_t)g * T);   // coalesced 32B per thread
    dst[0] = make_float4(o[0], o[1], o[2], o[3]);
    dst[1] = make_float4(o[4], o[5], o[6], o[7]);
}

extern "C" void kernel_launch(void* const* d_in, const int* in_sizes, int n_in,
                              void* d_out, int out_size, void* d_ws, size_t ws_size,
                              hipStream_t stream) {
    const float* vals  = (const float*)d_in[0];
    const int*   rows  = (const int*)d_in[1];
    const int*   cols  = (const int*)d_in[2];
    const int*   sidx  = (const int*)d_in[3];
    const int*   gi    = (const int*)d_in[4];
    const float* slope = (const float*)d_in[5];
    const float* rawb  = (const float*)d_in[6];
    const float* inputs = (const float*)d_in[7];
    float* out = (float*)d_out;

    // Workspace layout with time-aliasing (~103 MB):
    // Region A (51.2MB): pk during sort; after k_sortbin reused for St/Xin/slope/bias.
    // Region B (51.2MB): counts during sort prep (1.3MB); then pk2 (written by k_sortbin).
    // Region C: binTot, binBase, rowPtr (persistent, small).
    char* ws = (char*)d_ws;
    uint2*    pk     = (uint2*)ws;                         // [0, 51.2MB)
    float*    St     = (float*)ws;                         // 25.6MB (aliases pk, used after sort)
    float*    Xin0   = (float*)(ws + 25600000);            // 3.2MB
    float*    Xin1   = (float*)(ws + 28800000);            // 3.2MB
    float*    slopeN = (float*)(ws + 32000000);            // 0.4MB
    float*    biasN  = (float*)(ws + 32400000);            // 0.4MB
    char*     wsB    = ws + 51200000;
    uint2*    pk2    = (uint2*)wsB;                        // 51.2MB
    unsigned* counts = (unsigned*)wsB;                     // 1.23MB (dead before pk2 written)
    char*     wsC    = wsB + 51200000;
    unsigned* binTot  = (unsigned*)(wsC);                  // 1.6KB
    unsigned* binBase = (unsigned*)(wsC + 4096);           // 1.6KB
    unsigned* rowPtr  = (unsigned*)(wsC + 8192);           // 400KB
    size_t need = 102400000 + 8192 + (size_t)(N + 1) * 4 + 256;
    if (need > ws_size) return;   // workspace too small

    // ---- one-time sort to CSR ----
    k_hist<<<NCHUNKS, 256, 0, stream>>>(rows, counts);
    k_scan_chunks<<<NBINS1, 64, 0, stream>>>(counts, binTot);
    k_scan_bins<<<1, 64, 0, stream>>>(binTot, binBase);
    k_scatter<<<NCHUNKS, 512, 0, stream>>>(rows, cols, vals, binBase, counts, pk);
    k_sortbin<<<NBINS1, 256, 0, stream>>>(pk, binBase, pk2, rowPtr);
    // region A now reusable:
    k_precompute_sb<<<(N + 255) / 256, 256, 0, stream>>>(gi, slope, rawb, slopeN, biasN);

    // t=0 input: zeros + sensory (uses real sidx)
    hipMemsetAsync(Xin0, 0, (size_t)N * B * 4, stream);
    k_sensory<<<(S * B + 255) / 256, 256, 0, stream>>>(inputs, sidx, Xin0, 0);

    float* Xcur = Xin0;
    float* Xnxt = Xin1;
    for (int t = 0; t < T; ++t) {
        // one wave per row: N waves = ceil(N/4) blocks of 256 threads
        k_step<<<(N + 3) / 4, 256, 0, stream>>>(
            pk2, rowPtr, Xcur, slopeN, biasN, St + (size_t)t * N * B, Xnxt,
            inputs, t + 1, (t + 1 < T) ? 1 : 0);
        float* tmp = Xcur; Xcur = Xnxt; Xnxt = tmp;
    }
    k_transpose<<<(N * B + 255) / 256, 256, 0, stream>>>(St, out);
}

// Round 6
// 547.408 us; speedup vs baseline: 5.2256x; 1.0278x over previous
//
#include <hip/hip_runtime.h>
#include <cstdint>
#include <cstddef>

// Problem constants (fixed instance).
constexpr int N       = 100000;     // neurons
constexpr int NNZ     = 6400000;    // edges
constexpr int B       = 8;          // batch
constexpr int T       = 8;          // timesteps
constexpr int S       = 5000;       // sensory neurons (sensory_indices = arange(S))
constexpr int BIN1_BITS = 8;
constexpr int BIN1    = 1 << BIN1_BITS;              // 256 rows per L1 bin
constexpr int NBINS1  = (N + BIN1 - 1) / BIN1;       // 391
constexpr int CHUNK   = 8192;                        // edges per sort block
constexpr int NCHUNKS = (NNZ + CHUNK - 1) / CHUNK;   // 782
constexpr int STAGE_CAP = 17408;                     // bin stage: mean 16384 + 8 sigma
constexpr float THRESH = 0.01f;

// ---------- prep: per-neuron slope / softplus(bias) ----------
__global__ void k_precompute_sb(const int* __restrict__ gi,
                                const float* __restrict__ slope,
                                const float* __restrict__ raw_biases,
                                float* __restrict__ slopeN,
                                float* __restrict__ biasN) {
    int i = blockIdx.x * 256 + threadIdx.x;
    if (i < N) {
        int g = gi[i];
        slopeN[i] = slope[g];
        float rb = raw_biases[g];
        biasN[i] = (rb > 20.0f) ? rb : log1pf(expf(rb));   // softplus
    }
}

// ---------- pass 1: per-(bin,chunk) histogram ----------
__global__ void k_hist(const int* __restrict__ rows, unsigned* __restrict__ counts) {
    __shared__ unsigned hist[NBINS1];
    int tid = threadIdx.x, chunk = blockIdx.x;
    for (int i = tid; i < NBINS1; i += 256) hist[i] = 0;
    __syncthreads();
    int base = chunk * CHUNK;
    #pragma unroll 4
    for (int it = 0; it < CHUNK / 256; ++it) {
        int e = base + it * 256 + tid;
        if (e < NNZ) atomicAdd(&hist[((unsigned)rows[e]) >> BIN1_BITS], 1u);
    }
    __syncthreads();
    for (int i = tid; i < NBINS1; i += 256) counts[(size_t)i * NCHUNKS + chunk] = hist[i];
}

// ---------- pass 2a: per-bin exclusive scan across chunks ----------
__global__ void k_scan_chunks(unsigned* __restrict__ counts, unsigned* __restrict__ binTot) {
    int bin = blockIdx.x, lane = threadIdx.x;   // 64 threads
    unsigned carry = 0;
    for (int bse = 0; bse < NCHUNKS; bse += 64) {
        int idx = bse + lane;
        unsigned v = (idx < NCHUNKS) ? counts[(size_t)bin * NCHUNKS + idx] : 0u;
        unsigned x = v;
        #pragma unroll
        for (int off = 1; off < 64; off <<= 1) {
            unsigned y = __shfl_up(x, off, 64);
            if (lane >= off) x += y;
        }
        if (idx < NCHUNKS) counts[(size_t)bin * NCHUNKS + idx] = x - v + carry;
        carry += __shfl(x, 63, 64);
    }
    if (lane == 0) binTot[bin] = carry;
}

// ---------- pass 2b: exclusive scan over bins ----------
__global__ void k_scan_bins(const unsigned* __restrict__ binTot, unsigned* __restrict__ binBase) {
    int lane = threadIdx.x;   // 64 threads, 1 block
    unsigned carry = 0;
    for (int bse = 0; bse < NBINS1; bse += 64) {
        int idx = bse + lane;
        unsigned v = (idx < NBINS1) ? binTot[idx] : 0u;
        unsigned x = v;
        #pragma unroll
        for (int off = 1; off < 64; off <<= 1) {
            unsigned y = __shfl_up(x, off, 64);
            if (lane >= off) x += y;
        }
        if (idx < NBINS1) binBase[idx] = x - v + carry;
        carry += __shfl(x, 63, 64);
    }
    if (lane == 0) binBase[NBINS1] = carry;   // == NNZ
}

// ---------- pass 3: LDS-staged scatter — sorted-run (coalesced) global writes ----------
__global__ __launch_bounds__(512)
void k_scatter(const int* __restrict__ rows, const int* __restrict__ cols,
               const float* __restrict__ vals,
               const unsigned* __restrict__ binBase,
               const unsigned* __restrict__ counts,
               uint2* __restrict__ pk) {
    __shared__ uint2    stage[CHUNK];      // 64 KB
    __shared__ unsigned lcnt[NBINS1];      // hist, then run-end cursor
    __shared__ unsigned lofs[NBINS1 + 1];  // exclusive scan (run starts)
    __shared__ unsigned gdst[NBINS1];      // global dest base of this chunk's run
    int tid = threadIdx.x, chunk = blockIdx.x;
    int base = chunk * CHUNK;
    for (int i = tid; i < NBINS1; i += 512) lcnt[i] = 0;
    __syncthreads();
    // local histogram
    for (int i = tid; i < CHUNK; i += 512) {
        int e = base + i;
        if (e < NNZ) atomicAdd(&lcnt[((unsigned)rows[e]) >> BIN1_BITS], 1u);
    }
    __syncthreads();
    // exclusive scan of lcnt -> lofs (wave 0, sequential-carry over 64-wide tiles)
    if (tid < 64) {
        unsigned carry = 0;
        for (int bse = 0; bse < NBINS1; bse += 64) {
            int idx = bse + tid;
            unsigned v = (idx < NBINS1) ? lcnt[idx] : 0u;
            unsigned x = v;
            #pragma unroll
            for (int off = 1; off < 64; off <<= 1) {
                unsigned y = __shfl_up(x, off, 64);
                if (tid >= off) x += y;
            }
            if (idx < NBINS1) lofs[idx] = x - v + carry;
            carry += __shfl(x, 63, 64);
        }
        if (tid == 0) lofs[NBINS1] = carry;
    }
    __syncthreads();
    if (tid < NBINS1) {
        lcnt[tid] = lofs[tid];                                      // cursor
        gdst[tid] = binBase[tid] + counts[(size_t)tid * NCHUNKS + chunk];
    }
    __syncthreads();
    // scatter into LDS (sorted by bin)
    for (int i = tid; i < CHUNK; i += 512) {
        int e = base + i;
        if (e < NNZ) {
            unsigned r = (unsigned)rows[e];
            unsigned c = (unsigned)cols[e];
            float    v = vals[e];
            unsigned b1 = r >> BIN1_BITS, lr = r & (BIN1 - 1);
            unsigned pos = atomicAdd(&lcnt[b1], 1u);
            stage[pos] = make_uint2(__float_as_uint(v), c | (lr << 17));
        }
    }
    __syncthreads();
    // write out per-bin runs, lanes -> consecutive addresses (merged bursts)
    int wave = tid >> 6, lane = tid & 63;
    for (int b1 = wave; b1 < NBINS1; b1 += 8) {
        unsigned s = lofs[b1], epos = lcnt[b1];   // run [s, epos)
        unsigned g = gdst[b1];
        for (unsigned j = s + lane; j < epos; j += 64)
            pk[(size_t)g + (j - s)] = stage[j];
    }
}

// ---------- pass 4: within-bin counting sort, LDS-staged, coalesced write -> CSR ----------
__global__ __launch_bounds__(512)
void k_sortbin(const uint2* __restrict__ pk,
               const unsigned* __restrict__ binBase,
               uint2* __restrict__ pk2,
               unsigned* __restrict__ rowPtr) {
    __shared__ uint2    stage[STAGE_CAP];   // 139.3 KB
    __shared__ unsigned cnt[BIN1];
    __shared__ unsigned ofs[BIN1];
    int tid = threadIdx.x, bin = blockIdx.x;
    if (tid < BIN1) cnt[tid] = 0;
    __syncthreads();
    unsigned s = binBase[bin], e = binBase[bin + 1];
    unsigned total = e - s;
    for (unsigned i = s + tid; i < e; i += 512)
        atomicAdd(&cnt[pk[i].y >> 17], 1u);   // int LDS atomic (native)
    __syncthreads();
    if (tid < BIN1) ofs[tid] = cnt[tid];
    __syncthreads();
    // Hillis-Steele inclusive scan of 256 entries
    for (int off = 1; off < BIN1; off <<= 1) {
        unsigned v = (tid < BIN1 && tid >= off) ? ofs[tid - off] : 0u;
        __syncthreads();
        if (tid < BIN1) ofs[tid] += v;
        __syncthreads();
    }
    if (tid < BIN1) {
        unsigned excl = ofs[tid] - cnt[tid];
        int row = bin * BIN1 + tid;
        if (row <= N) rowPtr[row] = s + excl;   // row==N covered in last bin
        cnt[tid] = excl;                        // local stage cursor
    }
    __syncthreads();
    if (total <= (unsigned)STAGE_CAP) {
        // sort into LDS stage, then write out contiguously (coalesced bursts)
        for (unsigned i = s + tid; i < e; i += 512) {
            uint2 p = pk[i];
            unsigned pos = atomicAdd(&cnt[p.y >> 17], 1u);
            stage[pos] = make_uint2(p.x, p.y & 0x1FFFFu);   // (val, col)
        }
        __syncthreads();
        for (unsigned j = tid; j < total; j += 512)
            pk2[(size_t)s + j] = stage[j];
    } else {
        // fallback (never expected with fixed data): direct scattered write
        for (unsigned i = s + tid; i < e; i += 512) {
            uint2 p = pk[i];
            unsigned pos = atomicAdd(&cnt[p.y >> 17], 1u);
            pk2[(size_t)s + pos] = make_uint2(p.x, p.y & 0x1FFFFu);
        }
    }
}

// ---------- sensory injection for t=0 (clip + scatter-add) ----------
__global__ void k_sensory(const float* __restrict__ inputs, const int* __restrict__ sidx,
                          float* __restrict__ X, int t) {
    int idx = blockIdx.x * 256 + threadIdx.x;
    if (idx < S * B) {
        int s = idx >> 3, b = idx & 7;
        float val = inputs[((size_t)b * S + s) * T + t];
        val = (val >= THRESH) ? fminf(val, 1.0f) : 0.0f;
        atomicAdd(&X[(size_t)sidx[s] * B + b], val);
    }
}

// ---------- main step: CSR SpMV, one wave per row, register accumulation ----------
__global__ __launch_bounds__(256)
void k_step(const uint2* __restrict__ pk2,
            const unsigned* __restrict__ rowPtr,
            const float* __restrict__ Xin,
            const float* __restrict__ slopeN,
            const float* __restrict__ biasN,
            float* __restrict__ Sout,     // activation output (N,B) = this step's state
            float* __restrict__ Xnext,    // next step's input (sensory fused if has_next)
            const float* __restrict__ inputs, int tnext, int has_next) {
    int wid  = (int)((blockIdx.x * 256u + threadIdx.x) >> 6);   // row = global wave id
    int lane = threadIdx.x & 63;
    if (wid >= N) return;
    unsigned e0 = rowPtr[wid], e1 = rowPtr[wid + 1];
    float a0=0.f,a1=0.f,a2=0.f,a3=0.f,a4=0.f,a5=0.f,a6=0.f,a7=0.f;
    for (unsigned e = e0 + lane; e < e1; e += 64) {
        uint2 p = pk2[e];
        float v = __uint_as_float(p.x);
        const float4* fx = (const float4*)(Xin + (size_t)p.y * B);
        float4 x0 = fx[0], x1 = fx[1];
        a0 += v * x0.x; a1 += v * x0.y; a2 += v * x0.z; a3 += v * x0.w;
        a4 += v * x1.x; a5 += v * x1.y; a6 += v * x1.z; a7 += v * x1.w;
    }
    // Fold 8 accumulators so lane ends up holding total for b = lane&7.
    int l1 = lane & 1, l2 = lane & 2, l4 = lane & 4;
    float k0 = l1 ? a1 : a0, s0 = l1 ? a0 : a1;
    float k1 = l1 ? a3 : a2, s1 = l1 ? a2 : a3;
    float k2 = l1 ? a5 : a4, s2 = l1 ? a4 : a5;
    float k3 = l1 ? a7 : a6, s3 = l1 ? a6 : a7;
    k0 += __shfl_xor(s0, 1, 64);
    k1 += __shfl_xor(s1, 1, 64);
    k2 += __shfl_xor(s2, 1, 64);
    k3 += __shfl_xor(s3, 1, 64);
    float m0 = l2 ? k1 : k0, t0 = l2 ? k0 : k1;
    float m1 = l2 ? k3 : k2, t1 = l2 ? k2 : k3;
    m0 += __shfl_xor(t0, 2, 64);
    m1 += __shfl_xor(t1, 2, 64);
    float r = l4 ? m1 : m0, u = l4 ? m0 : m1;
    r += __shfl_xor(u, 4, 64);
    r += __shfl_xor(r, 8, 64);
    r += __shfl_xor(r, 16, 64);
    r += __shfl_xor(r, 32, 64);
    // activation
    float sl = slopeN[wid], bi = biasN[wid];
    float y = sl * r + bi;
    y = (y >= THRESH) ? y : 0.f;
    float o = tanhf(y);
    if (lane < 8) {
        size_t idx = (size_t)wid * B + lane;
        Sout[idx] = o;
        float xn = o;
        if (has_next && wid < S) {   // sensory_indices == arange(S)
            float val = inputs[((size_t)lane * S + wid) * T + tnext];
            val = (val >= THRESH) ? fminf(val, 1.0f) : 0.0f;
            xn += val;
        }
        Xnext[idx] = xn;
    }
}

// ---------- final transpose: St (T,N,B) f32 -> out (B,N,T) f32 ----------
__global__ void k_transpose(const float* __restrict__ St, float* __restrict__ out) {
    int g = blockIdx.x * 256 + threadIdx.x;      // g = b*N + r
    if (g >= N * B) return;
    int b = g / N;
    int r = g - b * N;
    float o[T];
    #pragma unroll
    for (int t = 0; t < T; ++t)
        o[t] = St[(size_t)t * N * B + (size_t)r * B + b];
    float4* dst = (float4*)(out + (size_t)g * T);   // coalesced 32B per thread
    dst[0] = make_float4(o[0], o[1], o[2], o[3]);
    dst[1] = make_float4(o[4], o[5], o[6], o[7]);
}

extern "C" void kernel_launch(void* const* d_in, const int* in_sizes, int n_in,
                              void* d_out, int out_size, void* d_ws, size_t ws_size,
                              hipStream_t stream) {
    const float* vals  = (const float*)d_in[0];
    const int*   rows  = (const int*)d_in[1];
    const int*   cols  = (const int*)d_in[2];
    const int*   sidx  = (const int*)d_in[3];
    const int*   gi    = (const int*)d_in[4];
    const float* slope = (const float*)d_in[5];
    const float* rawb  = (const float*)d_in[6];
    const float* inputs = (const float*)d_in[7];
    float* out = (float*)d_out;

    // Workspace layout with time-aliasing (~103 MB):
    // Region A (51.2MB): pk during sort; after k_sortbin reused for St/Xin/slope/bias.
    // Region B (51.2MB): counts during sort prep (1.3MB); then pk2 (written by k_sortbin).
    // Region C: binTot, binBase, rowPtr (persistent, small).
    char* ws = (char*)d_ws;
    uint2*    pk     = (uint2*)ws;                         // [0, 51.2MB)
    float*    St     = (float*)ws;                         // 25.6MB (aliases pk, used after sort)
    float*    Xin0   = (float*)(ws + 25600000);            // 3.2MB
    float*    Xin1   = (float*)(ws + 28800000);            // 3.2MB
    float*    slopeN = (float*)(ws + 32000000);            // 0.4MB
    float*    biasN  = (float*)(ws + 32400000);            // 0.4MB
    char*     wsB    = ws + 51200000;
    uint2*    pk2    = (uint2*)wsB;                        // 51.2MB
    unsigned* counts = (unsigned*)wsB;                     // 1.23MB (dead before pk2 written)
    char*     wsC    = wsB + 51200000;
    unsigned* binTot  = (unsigned*)(wsC);                  // 1.6KB
    unsigned* binBase = (unsigned*)(wsC + 4096);           // 1.6KB
    unsigned* rowPtr  = (unsigned*)(wsC + 8192);           // 400KB
    size_t need = 102400000 + 8192 + (size_t)(N + 1) * 4 + 256;
    if (need > ws_size) return;   // workspace too small

    // ---- one-time sort to CSR ----
    k_hist<<<NCHUNKS, 256, 0, stream>>>(rows, counts);
    k_scan_chunks<<<NBINS1, 64, 0, stream>>>(counts, binTot);
    k_scan_bins<<<1, 64, 0, stream>>>(binTot, binBase);
    k_scatter<<<NCHUNKS, 512, 0, stream>>>(rows, cols, vals, binBase, counts, pk);
    k_sortbin<<<NBINS1, 512, 0, stream>>>(pk, binBase, pk2, rowPtr);
    // region A now reusable:
    k_precompute_sb<<<(N + 255) / 256, 256, 0, stream>>>(gi, slope, rawb, slopeN, biasN);

    // t=0 input: zeros + sensory (uses real sidx)
    hipMemsetAsync(Xin0, 0, (size_t)N * B * 4, stream);
    k_sensory<<<(S * B + 255) / 256, 256, 0, stream>>>(inputs, sidx, Xin0, 0);

    float* Xcur = Xin0;
    float* Xnxt = Xin1;
    for (int t = 0; t < T; ++t) {
        // one wave per row: N waves = ceil(N/4) blocks of 256 threads
        k_step<<<(N + 3) / 4, 256, 0, stream>>>(
            pk2, rowPtr, Xcur, slopeN, biasN, St + (size_t)t * N * B, Xnxt,
            inputs, t + 1, (t + 1 < T) ? 1 : 0);
        float* tmp = Xcur; Xcur = Xnxt; Xnxt = tmp;
    }
    k_transpose<<<(N * B + 255) / 256, 256, 0, stream>>>(St, out);
}